// Round 6
// baseline (505.416 us; speedup 1.0000x reference)
//
#include <hip/hip_runtime.h>
#include <stdint.h>

#define NN 2048
#define EE 65536
#define XSN ((size_t)NN*4096)   // elems per XS matrix [N][64][64]
#define XIN ((size_t)NN*128)    // elems per XI matrix [N][64][2]

typedef unsigned short u16;
typedef __bf16 bf16x8 __attribute__((ext_vector_type(8)));
typedef float f32x4 __attribute__((ext_vector_type(4)));
typedef float f32x2 __attribute__((ext_vector_type(2)));

__device__ __forceinline__ float bf2f(u16 h){ return __uint_as_float(((unsigned)h)<<16); }
__device__ __forceinline__ u16 f2bf(float f){
  unsigned u = __float_as_uint(f);
  u += 0x7fffu + ((u>>16)&1u);
  return (u16)(u>>16);
}
__device__ __forceinline__ float loadf(const void* p, size_t i, int bfflag){
  return bfflag ? bf2f(((const u16*)p)[i]) : ((const float*)p)[i];
}
__device__ __forceinline__ f32x2 up2(unsigned u){
  f32x2 r; r.x = __uint_as_float(u<<16); r.y = __uint_as_float(u & 0xffff0000u); return r;
}
__device__ __forceinline__ unsigned pk2(f32x2 t){
  return (unsigned)f2bf(t.x) | ((unsigned)f2bf(t.y)<<16);
}
__device__ __forceinline__ void accv(float v, uint4 d, f32x2* a){
  f32x2 vv = {v, v};
  a[0] += vv*up2(d.x); a[1] += vv*up2(d.y);
  a[2] += vv*up2(d.z); a[3] += vv*up2(d.w);
}

// dtype probe: vals1 ~ U[0,1/32). bf16 -> every u16 in [0x2800,0x3D80); f32 low-u16 ~uniform.
__global__ void probe_k(const unsigned* __restrict__ vals, int* __restrict__ flag){
  int cnt = 0;
  for (int i=0;i<64;i++){
    unsigned lo = vals[i] & 0xffffu;
    if (lo >= 0x2800u && lo < 0x3D80u) cnt++;
  }
  *flag = (cnt >= 32) ? 1 : 0;
}

__global__ void hist2_k(const int* __restrict__ e1, const int* __restrict__ e2,
                        int* __restrict__ cnt){
  int b = blockIdx.x;
  if (b < 256) atomicAdd(&cnt[e1[b*256 + threadIdx.x]], 1);
  else atomicAdd(&cnt[2048 + e2[(b-256)*256 + threadIdx.x]], 1);
}

__global__ void scan2_k(const int* __restrict__ cntA, int* __restrict__ rpA, int* __restrict__ curA){
  __shared__ int s[1024];
  const int* cnt = cntA + blockIdx.x*2048;
  int* rp  = rpA  + blockIdx.x*2049;
  int* cur = curA + blockIdx.x*2048;
  int t = threadIdx.x;
  int c0 = cnt[2*t], c1 = cnt[2*t+1];
  int ps = c0 + c1;
  s[t] = ps;
  __syncthreads();
  for (int off=1; off<1024; off<<=1){
    int v = (t>=off) ? s[t-off] : 0;
    __syncthreads();
    s[t] += v;
    __syncthreads();
  }
  int excl = s[t] - ps;
  rp[2*t] = excl;  cur[2*t] = excl;
  rp[2*t+1] = excl + c0;  cur[2*t+1] = excl + c0;
  if (t==0) rp[2048] = EE;
}

__global__ void scatter2_k(const int* __restrict__ e1, const void* __restrict__ v1,
                           const int* __restrict__ e2, const void* __restrict__ v2,
                           int* __restrict__ curA, int2* __restrict__ scvA,
                           const int* __restrict__ flag){
  int bfflag = *flag;
  int b = blockIdx.x;
  const int* rows; const int* cols; const void* vals; int* cur; int2* scv; int e;
  if (b < 256){ rows=e1; cols=e1+EE; vals=v1; cur=curA; scv=scvA; e=b*256+threadIdx.x; }
  else { rows=e2; cols=e2+EE; vals=v2; cur=curA+2048; scv=scvA+EE; e=(b-256)*256+threadIdx.x; }
  int r = rows[e];
  int p = atomicAdd(&cur[r], 1);
  int2 cv; cv.x = cols[e]; cv.y = __float_as_int(loadf(vals, e, bfflag));
  scv[p] = cv;
}

// Pack W into MFMA B-frag order. Physical K order (state-first):
//   kk in [0,320): m = kk>>6, logical f = (kk&63)+2   (state features)
//   kk in [320,330): t = kk-320, m = t>>1, f = t&1     (input features)
//   kk in [330,352): zero pad
// Wf[((q*OT+t)*64 + L)*8 + j], o = t*16+(L&15), kk = q*32+(L>>4)*8+j
__global__ void pack2_k(const void* __restrict__ Wg, const void* __restrict__ Wc,
                        u16* __restrict__ Wfg, u16* __restrict__ Wfc,
                        const int* __restrict__ flag){
  int bfflag = *flag;
  int b = blockIdx.x;
  const void* W; u16* Wf; int O, OT, i;
  if (b < 176){ W=Wg; Wf=Wfg; O=128; OT=8; i=b*256+threadIdx.x; }
  else { W=Wc; Wf=Wfc; O=64; OT=4; i=(b-176)*256+threadIdx.x; }
  int j = i & 7, L = (i>>3)&63, tq = i>>9;
  int t = tq % OT, q = tq / OT;
  int o = t*16 + (L&15);
  int kk = q*32 + (L>>4)*8 + j;
  float v = 0.f;
  if (kk < 320){ int m = kk>>6, f = (kk&63)+2; v = loadf(W, (size_t)(f*5+m)*O + o, bfflag); }
  else if (kk < 330){ int tt = kk-320; int m = tt>>1, f = tt&1; v = loadf(W, (size_t)(f*5+m)*O + o, bfflag); }
  Wf[i] = f2bf(v);
}

__global__ void build_x0_k(const void* __restrict__ inp, const void* __restrict__ st,
                           u16* __restrict__ XSb, u16* __restrict__ XIb,
                           const int* __restrict__ flag){
  int bfflag = *flag, n = blockIdx.x, tid = threadIdx.x;
  if (bfflag){
    const uint4* sp = (const uint4*)st;
    uint4* xp = (uint4*)(XSb + (size_t)n*4096);
    #pragma unroll
    for (int it=0; it<2; ++it){
      int r = tid + it*256;     // [0,512): b = r>>3, v4 = r&7
      int b = r>>3, v4 = r&7;
      xp[r] = sp[(size_t)b*(NN*8) + (size_t)n*8 + v4];
    }
    if (tid < 64){
      ((unsigned*)XIb)[n*64 + tid] = ((const unsigned*)inp)[(size_t)tid*NN + n];
    }
  } else {
    for (int i=tid; i<4096; i+=256){
      int b=i>>6, f=i&63;
      XSb[(size_t)n*4096+i] = f2bf(((const float*)st)[(size_t)b*(NN*64) + n*64 + f]);
    }
    for (int i=tid; i<128; i+=256){
      int b=i>>1, f=i&1;
      XIb[(size_t)n*128+i] = f2bf(((const float*)inp)[(size_t)b*(NN*2) + n*2 + f]);
    }
  }
}

// Diffusion hop for BOTH supports (sup = blockIdx.y).
// CHEB=0: X_dst = S X0        (src m=0, dst m = sup?3:1)
// CHEB=1: X_dst = 2 S X_src - X0  (src m = sup?3:1, dst m = sup?4:2)
// grid.x = NN*8 (XS chunks, ch=bx&7 pins chunk->XCD) + NN/2 (XI half-wave blocks).
template<int CHEB>
__global__ __launch_bounds__(64) void spmm_k(
    u16* __restrict__ XSb, u16* __restrict__ XIb,
    const int* __restrict__ rpA, const int2* __restrict__ scvA){
  int sup = blockIdx.y;
  const int* rp = rpA + sup*2049;
  const int2* scv = scvA + sup*EE;
  const int srcm = CHEB ? (sup?3:1) : 0;
  const int dstm = CHEB ? (sup?4:2) : (sup?3:1);
  int tid = threadIdx.x;
  int bx = blockIdx.x;
  if (bx < NN*8){
    int ch = bx & 7, n = bx >> 3;
    int e0 = rp[n], e1 = rp[n+1];
    const uint4* src = (const uint4*)(XSb + srcm*XSN);
    int off = ch*64 + tid;
    f32x2 a[4] = {{0.f,0.f},{0.f,0.f},{0.f,0.f},{0.f,0.f}};
    int e = e0;
    for (; e+3 < e1; e += 4){
      int2 c0=scv[e], c1=scv[e+1], c2=scv[e+2], c3=scv[e+3];
      uint4 d0 = src[((size_t)c0.x<<9) + off];
      uint4 d1 = src[((size_t)c1.x<<9) + off];
      uint4 d2 = src[((size_t)c2.x<<9) + off];
      uint4 d3 = src[((size_t)c3.x<<9) + off];
      accv(__int_as_float(c0.y), d0, a);
      accv(__int_as_float(c1.y), d1, a);
      accv(__int_as_float(c2.y), d2, a);
      accv(__int_as_float(c3.y), d3, a);
    }
    for (; e < e1; ++e){
      int2 c0 = scv[e];
      accv(__int_as_float(c0.y), src[((size_t)c0.x<<9) + off], a);
    }
    uint4* dst = (uint4*)(XSb + dstm*XSN);
    uint4 w;
    if (CHEB){
      uint4 o = ((const uint4*)XSb)[((size_t)n<<9) + off];
      f32x2 t;
      t = 2.f*a[0] - up2(o.x); w.x = pk2(t);
      t = 2.f*a[1] - up2(o.y); w.y = pk2(t);
      t = 2.f*a[2] - up2(o.z); w.z = pk2(t);
      t = 2.f*a[3] - up2(o.w); w.w = pk2(t);
    } else {
      w.x = pk2(a[0]); w.y = pk2(a[1]); w.z = pk2(a[2]); w.w = pk2(a[3]);
    }
    dst[((size_t)n<<9) + off] = w;
  } else {
    // XI part: 2 nodes per block, half-wave each; 32 uint2 per row.
    int idx = bx - NN*8;
    int n = idx*2 + (tid>>5), m = tid & 31;
    int e0 = rp[n], e1 = rp[n+1];
    const uint2* src = (const uint2*)(XIb + srcm*XIN);
    f32x2 a0 = {0.f,0.f}, a1 = {0.f,0.f};
    for (int e=e0; e<e1; ++e){
      int2 cv = scv[e];
      uint2 d = src[cv.x*32 + m];
      f32x2 vv = {__int_as_float(cv.y), __int_as_float(cv.y)};
      a0 += vv*up2(d.x); a1 += vv*up2(d.y);
    }
    uint2* dst = (uint2*)(XIb + dstm*XIN);
    if (CHEB){
      uint2 o = ((const uint2*)XIb)[n*32 + m];
      a0 = 2.f*a0 - up2(o.x); a1 = 2.f*a1 - up2(o.y);
    }
    uint2 w; w.x = pk2(a0); w.y = pk2(a1);
    dst[n*32 + m] = w;
  }
}

// Load the 11 A-fragments for row-tile (n, rt4) directly from global.
// Physical K: k = m*64+f (state, q=0..9), k=320+2m+c (input, q=10), pad to 352.
// A-frag: row b = rt4*16 + (lane&15); k = q*32 + (lane>>4)*8 + j.
__device__ __forceinline__ void load_afrag(bf16x8* af, const u16* __restrict__ XSb,
                                           const unsigned* __restrict__ XI32,
                                           int n, int rt4, int m16, int q4){
  const uint4* xs4 = (const uint4*)XSb;
  int b = rt4*16 + m16;
  size_t base = (size_t)n*512 + (size_t)b*8 + q4;   // uint4 units
  #pragma unroll
  for (int q=0;q<10;q++){
    union { uint4 v; bf16x8 b; } u;
    u.v = xs4[(size_t)(q>>1)*(XSN/8) + base + (q&1)*4];
    af[q] = u.b;
  }
  union { unsigned w[4]; bf16x8 b; } t;
  t.w[0]=0; t.w[1]=0; t.w[2]=0; t.w[3]=0;
  if (q4==0){
    #pragma unroll
    for (int mm=0;mm<4;mm++) t.w[mm] = XI32[mm*(XIN/2) + n*64 + b];
  } else if (q4==1){
    t.w[0] = XI32[4*(XIN/2) + n*64 + b];
  }
  af[10] = t.b;
}

// Single-wave register GEMM: W frags live in VGPRs (loaded once), A frags stream
// from global (coalesced 64B lines), no LDS, no syncthreads.
// MODE 0 (gate, OT=8): sigmoid; t<4 -> r*state into XS0; t>=4 -> stash u in d_out.
// MODE 1 (cand, OT=4): c = tanh; new_state = u*state + (1-u)*c into d_out.
template<int OT, int MODE, int R, int DBUF>
__global__ __launch_bounds__(64,1) void gemm_k(
    u16* __restrict__ XSb, const u16* __restrict__ XIb,
    const u16* __restrict__ Wf, const void* __restrict__ bias,
    const void* __restrict__ state, void* __restrict__ outp,
    const int* __restrict__ flag){
  int lane = threadIdx.x;
  int m16 = lane & 15, q4 = lane >> 4;
  int bfflag = *flag;
  const bf16x8* wp = (const bf16x8*)Wf;
  bf16x8 wfr[11][OT];
  #pragma unroll
  for (int q=0;q<11;q++){
    #pragma unroll
    for (int t=0;t<OT;t++) wfr[q][t] = wp[(q*OT+t)*64 + lane];
  }
  const unsigned* XI32 = (const unsigned*)XIb;
  int rt0 = blockIdx.x * R;

  bf16x8 afA[11], afB[11];
  if (DBUF) load_afrag(afA, XSb, XI32, rt0>>2, rt0&3, m16, q4);
  #pragma unroll
  for (int i=0;i<R;i++){
    int rt = rt0 + i;
    int n = rt>>2, rt4 = rt&3;
    bf16x8* af;
    if (DBUF){
      af = (i&1) ? afB : afA;
      bf16x8* afn = (i&1) ? afA : afB;
      if (i+1 < R) load_afrag(afn, XSb, XI32, (rt+1)>>2, (rt+1)&3, m16, q4);
    } else {
      af = afA;
      load_afrag(afA, XSb, XI32, n, rt4, m16, q4);
    }
    f32x4 acc[OT];
    #pragma unroll
    for (int t=0;t<OT;t++) acc[t] = (f32x4){0.f,0.f,0.f,0.f};
    #pragma unroll
    for (int q=0;q<11;q++){
      #pragma unroll
      for (int t=0;t<OT;t++)
        acc[t] = __builtin_amdgcn_mfma_f32_16x16x32_bf16(af[q], wfr[q][t], acc[t], 0, 0, 0);
    }
    #pragma unroll
    for (int t=0;t<OT;t++){
      int o = t*16 + m16;
      float bo = loadf(bias, o, bfflag);
      #pragma unroll
      for (int r=0;r<4;r++){
        int b = rt4*16 + q4*4 + r;
        float x = acc[t][r] + bo;
        if (MODE==0){
          float s = 1.f/(1.f + __expf(-x));
          if (t < 4){
            float st = loadf(state, (size_t)b*(NN*64) + (size_t)n*64 + o, bfflag);
            XSb[(size_t)n*4096 + b*64 + o] = f2bf(s*st);
          } else {
            size_t idx = (size_t)b*(NN*64) + (size_t)n*64 + (o-64);
            if (bfflag) ((u16*)outp)[idx] = f2bf(s); else ((float*)outp)[idx] = s;
          }
        } else {
          float c = tanhf(x);
          size_t idx = (size_t)b*(NN*64) + (size_t)n*64 + o;
          float uu = bfflag ? bf2f(((const u16*)outp)[idx]) : ((const float*)outp)[idx];
          float st = loadf(state, idx, bfflag);
          float ns = uu*st + (1.f-uu)*c;
          if (bfflag) ((u16*)outp)[idx] = f2bf(ns); else ((float*)outp)[idx] = ns;
        }
      }
    }
  }
}

extern "C" void kernel_launch(void* const* d_in, const int* in_sizes, int n_in,
                              void* d_out, int out_size, void* d_ws, size_t ws_size,
                              hipStream_t stream) {
  const void* inputs = d_in[0];
  const void* state  = d_in[1];
  const int* edges1 = (const int*)d_in[2];
  const void* vals1  = d_in[3];
  const int* edges2 = (const int*)d_in[4];
  const void* vals2  = d_in[5];
  const void* Wg     = d_in[6];
  const void* bg     = d_in[7];
  const void* Wc     = d_in[8];
  const void* bc     = d_in[9];

  char* ws = (char*)d_ws;
  size_t off = 0;
  auto get = [&](size_t bytes)->void*{
    void* p = ws + off; off = (off + bytes + 255) & ~(size_t)255; return p;
  };
  u16* XSb = (u16*)get(5*XSN*2);   // 83.9 MB
  u16* XIb = (u16*)get(5*XIN*2);   // 2.6 MB
  u16* Wfg = (u16*)get(11*8*64*8*2);
  u16* Wfc = (u16*)get(11*4*64*8*2);
  int* cnt  = (int*)get(2*2048*4);
  int* rp   = (int*)get(2*2049*4);
  int* cur  = (int*)get(2*2048*4);
  int* flag = (int*)get(4);
  int2* scv = (int2*)get((size_t)2*EE*8);

  probe_k<<<1,1,0,stream>>>((const unsigned*)vals1, flag);
  hipMemsetAsync(cnt, 0, 2*2048*4, stream);
  hist2_k<<<512,256,0,stream>>>(edges1, edges2, cnt);
  scan2_k<<<2,1024,0,stream>>>(cnt, rp, cur);
  scatter2_k<<<512,256,0,stream>>>(edges1, vals1, edges2, vals2, cur, scv, flag);
  pack2_k<<<264,256,0,stream>>>(Wg, Wc, Wfg, Wfc, flag);
  build_x0_k<<<NN,256,0,stream>>>(inputs, state, XSb, XIb, flag);

  dim3 sg(NN*8 + NN/2, 2);
  // gate diffusion
  spmm_k<0><<<sg,64,0,stream>>>(XSb, XIb, rp, scv);
  spmm_k<1><<<sg,64,0,stream>>>(XSb, XIb, rp, scv);
  gemm_k<8,0,8,0><<<1024,64,0,stream>>>(XSb, XIb, Wfg, bg, state, d_out, flag);
  // candidate diffusion (XS0 now = r*state, XI0 = inputs)
  spmm_k<0><<<sg,64,0,stream>>>(XSb, XIb, rp, scv);
  spmm_k<1><<<sg,64,0,stream>>>(XSb, XIb, rp, scv);
  gemm_k<4,1,8,1><<<1024,64,0,stream>>>(XSb, XIb, Wfc, bc, state, d_out, flag);
}

// Round 8
// 447.040 us; speedup vs baseline: 1.1306x; 1.1306x over previous
//
#include <hip/hip_runtime.h>
#include <stdint.h>

#define NN 2048
#define EE 65536
#define APITCH 360              // LDS K-pitch: 352 used + pad; 720B rows -> 2-way bank alias only
#define XSN ((size_t)NN*4096)   // elems per XS matrix [N][64][64]
#define XIN ((size_t)NN*128)    // elems per XI matrix [N][64][2]

typedef unsigned short u16;
typedef __bf16 bf16x8 __attribute__((ext_vector_type(8)));
typedef float f32x4 __attribute__((ext_vector_type(4)));
typedef float f32x2 __attribute__((ext_vector_type(2)));

__device__ __forceinline__ float bf2f(u16 h){ return __uint_as_float(((unsigned)h)<<16); }
__device__ __forceinline__ u16 f2bf(float f){
  unsigned u = __float_as_uint(f);
  u += 0x7fffu + ((u>>16)&1u);
  return (u16)(u>>16);
}
__device__ __forceinline__ float loadf(const void* p, size_t i, int bfflag){
  return bfflag ? bf2f(((const u16*)p)[i]) : ((const float*)p)[i];
}
__device__ __forceinline__ f32x2 up2(unsigned u){
  f32x2 r; r.x = __uint_as_float(u<<16); r.y = __uint_as_float(u & 0xffff0000u); return r;
}
__device__ __forceinline__ unsigned pk2(f32x2 t){
  return (unsigned)f2bf(t.x) | ((unsigned)f2bf(t.y)<<16);
}
__device__ __forceinline__ void accv(float v, uint4 d, f32x2* a){
  f32x2 vv = {v, v};
  a[0] += vv*up2(d.x); a[1] += vv*up2(d.y);
  a[2] += vv*up2(d.z); a[3] += vv*up2(d.w);
}

// dtype probe: vals1 ~ U[0,1/32). bf16 -> every u16 in [0x2800,0x3D80); f32 low-u16 ~uniform.
__global__ void probe_k(const unsigned* __restrict__ vals, int* __restrict__ flag){
  int i = threadIdx.x;
  unsigned lo = vals[i] & 0xffffu;
  unsigned long long m = __ballot(lo >= 0x2800u && lo < 0x3D80u);
  if (i==0) *flag = (__popcll(m) >= 32) ? 1 : 0;
}

__global__ void hist2_k(const int* __restrict__ e1, const int* __restrict__ e2,
                        int* __restrict__ cnt){
  int b = blockIdx.x;
  if (b < 256) atomicAdd(&cnt[e1[b*256 + threadIdx.x]], 1);
  else atomicAdd(&cnt[2048 + e2[(b-256)*256 + threadIdx.x]], 1);
}

__global__ void scan2_k(const int* __restrict__ cntA, int* __restrict__ rpA, int* __restrict__ curA){
  __shared__ int s[1024];
  const int* cnt = cntA + blockIdx.x*2048;
  int* rp  = rpA  + blockIdx.x*2049;
  int* cur = curA + blockIdx.x*2048;
  int t = threadIdx.x;
  int c0 = cnt[2*t], c1 = cnt[2*t+1];
  int ps = c0 + c1;
  s[t] = ps;
  __syncthreads();
  for (int off=1; off<1024; off<<=1){
    int v = (t>=off) ? s[t-off] : 0;
    __syncthreads();
    s[t] += v;
    __syncthreads();
  }
  int excl = s[t] - ps;
  rp[2*t] = excl;  cur[2*t] = excl;
  rp[2*t+1] = excl + c0;  cur[2*t+1] = excl + c0;
  if (t==0) rp[2048] = EE;
}

__global__ void scatter2_k(const int* __restrict__ e1, const void* __restrict__ v1,
                           const int* __restrict__ e2, const void* __restrict__ v2,
                           int* __restrict__ curA, int2* __restrict__ scvA,
                           const int* __restrict__ flag){
  int bfflag = *flag;
  int b = blockIdx.x;
  const int* rows; const int* cols; const void* vals; int* cur; int2* scv; int e;
  if (b < 256){ rows=e1; cols=e1+EE; vals=v1; cur=curA; scv=scvA; e=b*256+threadIdx.x; }
  else { rows=e2; cols=e2+EE; vals=v2; cur=curA+2048; scv=scvA+EE; e=(b-256)*256+threadIdx.x; }
  int r = rows[e];
  int p = atomicAdd(&cur[r], 1);
  int2 cv; cv.x = cols[e]; cv.y = __float_as_int(loadf(vals, e, bfflag));
  scv[p] = cv;
}

// Pack W into MFMA B-frag order. Physical K order (state-first):
//   kk in [0,320): m = kk>>6, logical f = (kk&63)+2   (state features)
//   kk in [320,330): t = kk-320, m = t>>1, f = t&1     (input features)
//   kk in [330,352): zero pad
// Wf[((q*OT+t)*64 + L)*8 + j], o = t*16+(L&15), kk = q*32+(L>>4)*8+j
__global__ void pack2_k(const void* __restrict__ Wg, const void* __restrict__ Wc,
                        u16* __restrict__ Wfg, u16* __restrict__ Wfc,
                        const int* __restrict__ flag){
  int bfflag = *flag;
  int b = blockIdx.x;
  const void* W; u16* Wf; int O, OT, i;
  if (b < 176){ W=Wg; Wf=Wfg; O=128; OT=8; i=b*256+threadIdx.x; }
  else { W=Wc; Wf=Wfc; O=64; OT=4; i=(b-176)*256+threadIdx.x; }
  int j = i & 7, L = (i>>3)&63, tq = i>>9;
  int t = tq % OT, q = tq / OT;
  int o = t*16 + (L&15);
  int kk = q*32 + (L>>4)*8 + j;
  float v = 0.f;
  if (kk < 320){ int m = kk>>6, f = (kk&63)+2; v = loadf(W, (size_t)(f*5+m)*O + o, bfflag); }
  else if (kk < 330){ int tt = kk-320; int m = tt>>1, f = tt&1; v = loadf(W, (size_t)(f*5+m)*O + o, bfflag); }
  Wf[i] = f2bf(v);
}

__global__ void build_x0_k(const void* __restrict__ inp, const void* __restrict__ st,
                           u16* __restrict__ XSb, u16* __restrict__ XIb,
                           const int* __restrict__ flag){
  int bfflag = *flag, n = blockIdx.x, tid = threadIdx.x;
  if (bfflag){
    const uint4* sp = (const uint4*)st;
    uint4* xp = (uint4*)(XSb + (size_t)n*4096);
    #pragma unroll
    for (int it=0; it<2; ++it){
      int r = tid + it*256;     // [0,512): b = r>>3, v4 = r&7
      int b = r>>3, v4 = r&7;
      xp[r] = sp[(size_t)b*(NN*8) + (size_t)n*8 + v4];
    }
    if (tid < 64){
      ((unsigned*)XIb)[n*64 + tid] = ((const unsigned*)inp)[(size_t)tid*NN + n];
    }
  } else {
    for (int i=tid; i<4096; i+=256){
      int b=i>>6, f=i&63;
      XSb[(size_t)n*4096+i] = f2bf(((const float*)st)[(size_t)b*(NN*64) + n*64 + f]);
    }
    for (int i=tid; i<128; i+=256){
      int b=i>>1, f=i&1;
      XIb[(size_t)n*128+i] = f2bf(((const float*)inp)[(size_t)b*(NN*2) + n*2 + f]);
    }
  }
}

// Diffusion hop for BOTH supports (sup = blockIdx.y).
// CHEB=0: X_dst = S X0        (src m=0, dst m = sup?3:1)
// CHEB=1: X_dst = 2 S X_src - X0  (src m = sup?3:1, dst m = sup?4:2)
// grid.x = NN*8 (XS chunks, ch=bx&7 pins chunk->XCD) + NN/2 (XI half-wave blocks).
template<int CHEB>
__global__ __launch_bounds__(64) void spmm_k(
    u16* __restrict__ XSb, u16* __restrict__ XIb,
    const int* __restrict__ rpA, const int2* __restrict__ scvA){
  int sup = blockIdx.y;
  const int* rp = rpA + sup*2049;
  const int2* scv = scvA + sup*EE;
  const int srcm = CHEB ? (sup?3:1) : 0;
  const int dstm = CHEB ? (sup?4:2) : (sup?3:1);
  int tid = threadIdx.x;
  int bx = blockIdx.x;
  if (bx < NN*8){
    int ch = bx & 7, n = bx >> 3;
    int e0 = rp[n], e1 = rp[n+1];
    const uint4* src = (const uint4*)(XSb + srcm*XSN);
    int off = ch*64 + tid;
    f32x2 a[4] = {{0.f,0.f},{0.f,0.f},{0.f,0.f},{0.f,0.f}};
    int e = e0;
    for (; e+3 < e1; e += 4){
      int2 c0=scv[e], c1=scv[e+1], c2=scv[e+2], c3=scv[e+3];
      uint4 d0 = src[((size_t)c0.x<<9) + off];
      uint4 d1 = src[((size_t)c1.x<<9) + off];
      uint4 d2 = src[((size_t)c2.x<<9) + off];
      uint4 d3 = src[((size_t)c3.x<<9) + off];
      accv(__int_as_float(c0.y), d0, a);
      accv(__int_as_float(c1.y), d1, a);
      accv(__int_as_float(c2.y), d2, a);
      accv(__int_as_float(c3.y), d3, a);
    }
    for (; e < e1; ++e){
      int2 c0 = scv[e];
      accv(__int_as_float(c0.y), src[((size_t)c0.x<<9) + off], a);
    }
    uint4* dst = (uint4*)(XSb + dstm*XSN);
    uint4 w;
    if (CHEB){
      uint4 o = ((const uint4*)XSb)[((size_t)n<<9) + off];
      f32x2 t;
      t = 2.f*a[0] - up2(o.x); w.x = pk2(t);
      t = 2.f*a[1] - up2(o.y); w.y = pk2(t);
      t = 2.f*a[2] - up2(o.z); w.z = pk2(t);
      t = 2.f*a[3] - up2(o.w); w.w = pk2(t);
    } else {
      w.x = pk2(a[0]); w.y = pk2(a[1]); w.z = pk2(a[2]); w.w = pk2(a[3]);
    }
    dst[((size_t)n<<9) + off] = w;
  } else {
    // XI part: 2 nodes per block, half-wave each; 32 uint2 per row.
    int idx = bx - NN*8;
    int n = idx*2 + (tid>>5), m = tid & 31;
    int e0 = rp[n], e1 = rp[n+1];
    const uint2* src = (const uint2*)(XIb + srcm*XIN);
    f32x2 a0 = {0.f,0.f}, a1 = {0.f,0.f};
    for (int e=e0; e<e1; ++e){
      int2 cv = scv[e];
      uint2 d = src[cv.x*32 + m];
      f32x2 vv = {__int_as_float(cv.y), __int_as_float(cv.y)};
      a0 += vv*up2(d.x); a1 += vv*up2(d.y);
    }
    uint2* dst = (uint2*)(XIb + dstm*XIN);
    if (CHEB){
      uint2 o = ((const uint2*)XIb)[n*32 + m];
      a0 = 2.f*a0 - up2(o.x); a1 = 2.f*a1 - up2(o.y);
    }
    uint2 w; w.x = pk2(a0); w.y = pk2(a1);
    dst[n*32 + m] = w;
  }
}

// Block = 256 thr (4 waves), one node n per block. A(n) staged to LDS once
// (5 contiguous 8KB XS chunks + XI), physical K = m*64+f_state | 320+2m+c | pad.
// W-frags split across waves: wave w owns output tiles t = w + 4*i (i<TW=OT/4),
// so per-wave W stays register-resident (gate 88 VGPRs, cand 44).
// MODE 0 (gate): tile i=0 (o<64) -> r*state into XS0; i=1 -> u into d_out.
// MODE 1 (cand): c = tanh; new_state = u*state + (1-u)*c into d_out.
template<int OT, int MODE>
__global__ __launch_bounds__(256) void gemm_k(
    u16* __restrict__ XSb, const u16* __restrict__ XIb,
    const u16* __restrict__ Wf, const void* __restrict__ bias,
    const void* __restrict__ state, void* __restrict__ outp,
    const int* __restrict__ flag){
  __shared__ __align__(16) u16 A[64*APITCH];
  int tid = threadIdx.x, n = blockIdx.x;
  int bfflag = *flag;
  // stage XS: 5 matrices, each node-chunk is 8KB contiguous
  #pragma unroll
  for (int m=0;m<5;m++){
    const uint4* src = (const uint4*)(XSb + (size_t)m*XSN + ((size_t)n<<12));
    #pragma unroll
    for (int it=0; it<2; ++it){
      int r = tid + it*256;          // 512 uint4: b = r>>3, f0 = (r&7)*8
      uint4 d = src[r];
      int b = r>>3, f0 = (r&7)*8;
      *(uint4*)&A[b*APITCH + m*64 + f0] = d;
    }
  }
  // XI: 5 x 64 u32 (features 320+2m) -- strided loop (320 > blockDim!)
  for (int i=tid; i<320; i+=256){
    int m = i>>6, b = i&63;
    unsigned v = ((const unsigned*)XIb)[(size_t)m*(XIN/2) + n*64 + b];
    *(unsigned*)&A[b*APITCH + 320 + 2*m] = v;
  }
  // zero pad elems 330..359 per row (15 u32)
  for (int i=tid; i<64*15; i+=256){
    int b = i/15, j = i - b*15;
    *(unsigned*)&A[b*APITCH + 330 + 2*j] = 0;
  }
  // W-frags for this wave (regs only)
  const int TW = OT/4;
  int lane = tid & 63, w = tid >> 6;
  int m16 = lane & 15, q4 = lane >> 4;
  const bf16x8* wp = (const bf16x8*)Wf;
  bf16x8 wfr[11][TW];
  #pragma unroll
  for (int q=0;q<11;q++){
    #pragma unroll
    for (int i=0;i<TW;i++) wfr[q][i] = wp[(q*OT + (w + 4*i))*64 + lane];
  }
  __syncthreads();
  #pragma unroll
  for (int rt4=0; rt4<4; ++rt4){
    const u16* arow = A + (rt4*16 + m16)*APITCH + q4*8;
    f32x4 acc[TW];
    #pragma unroll
    for (int i=0;i<TW;i++) acc[i] = (f32x4){0.f,0.f,0.f,0.f};
    #pragma unroll
    for (int q=0;q<11;q++){
      bf16x8 af = *((const bf16x8*)(arow + q*32));
      #pragma unroll
      for (int i=0;i<TW;i++)
        acc[i] = __builtin_amdgcn_mfma_f32_16x16x32_bf16(af, wfr[q][i], acc[i], 0, 0, 0);
    }
    #pragma unroll
    for (int i=0;i<TW;i++){
      int t = w + 4*i;
      int o = t*16 + m16;
      float bo = loadf(bias, o, bfflag);
      #pragma unroll
      for (int r=0;r<4;r++){
        int b = rt4*16 + q4*4 + r;
        float x = acc[i][r] + bo;
        if (MODE==0){
          float s = 1.f/(1.f + __expf(-x));
          if (i==0){   // o < 64: r-gate -> r*state overwrites XS0(n)
            float st = loadf(state, (size_t)b*(NN*64) + (size_t)n*64 + o, bfflag);
            XSb[((size_t)n<<12) + b*64 + o] = f2bf(s*st);
          } else {     // o >= 64: u stashed in d_out
            size_t idx = (size_t)b*(NN*64) + (size_t)n*64 + (o-64);
            if (bfflag) ((u16*)outp)[idx] = f2bf(s); else ((float*)outp)[idx] = s;
          }
        } else {
          float c = tanhf(x);
          size_t idx = (size_t)b*(NN*64) + (size_t)n*64 + o;
          float uu = bfflag ? bf2f(((const u16*)outp)[idx]) : ((const float*)outp)[idx];
          float st = loadf(state, idx, bfflag);
          float ns = uu*st + (1.f-uu)*c;
          if (bfflag) ((u16*)outp)[idx] = f2bf(ns); else ((float*)outp)[idx] = ns;
        }
      }
    }
  }
}

extern "C" void kernel_launch(void* const* d_in, const int* in_sizes, int n_in,
                              void* d_out, int out_size, void* d_ws, size_t ws_size,
                              hipStream_t stream) {
  const void* inputs = d_in[0];
  const void* state  = d_in[1];
  const int* edges1 = (const int*)d_in[2];
  const void* vals1  = d_in[3];
  const int* edges2 = (const int*)d_in[4];
  const void* vals2  = d_in[5];
  const void* Wg     = d_in[6];
  const void* bg     = d_in[7];
  const void* Wc     = d_in[8];
  const void* bc     = d_in[9];

  char* ws = (char*)d_ws;
  size_t off = 0;
  auto get = [&](size_t bytes)->void*{
    void* p = ws + off; off = (off + bytes + 255) & ~(size_t)255; return p;
  };
  u16* XSb = (u16*)get(5*XSN*2);   // 83.9 MB
  u16* XIb = (u16*)get(5*XIN*2);   // 2.6 MB
  u16* Wfg = (u16*)get(11*8*64*8*2);
  u16* Wfc = (u16*)get(11*4*64*8*2);
  int* cnt  = (int*)get(2*2048*4);
  int* rp   = (int*)get(2*2049*4);
  int* cur  = (int*)get(2*2048*4);
  int* flag = (int*)get(4);
  int2* scv = (int2*)get((size_t)2*EE*8);

  probe_k<<<1,64,0,stream>>>((const unsigned*)vals1, flag);
  hipMemsetAsync(cnt, 0, 2*2048*4, stream);
  hist2_k<<<512,256,0,stream>>>(edges1, edges2, cnt);
  scan2_k<<<2,1024,0,stream>>>(cnt, rp, cur);
  scatter2_k<<<512,256,0,stream>>>(edges1, vals1, edges2, vals2, cur, scv, flag);
  pack2_k<<<264,256,0,stream>>>(Wg, Wc, Wfg, Wfc, flag);
  build_x0_k<<<NN,256,0,stream>>>(inputs, state, XSb, XIb, flag);

  dim3 sg(NN*8 + NN/2, 2);
  // gate diffusion
  spmm_k<0><<<sg,64,0,stream>>>(XSb, XIb, rp, scv);
  spmm_k<1><<<sg,64,0,stream>>>(XSb, XIb, rp, scv);
  gemm_k<8,0><<<NN,256,0,stream>>>(XSb, XIb, Wfg, bg, state, d_out, flag);
  // candidate diffusion (XS0 now = r*state, XI0 = inputs)
  spmm_k<0><<<sg,64,0,stream>>>(XSb, XIb, rp, scv);
  spmm_k<1><<<sg,64,0,stream>>>(XSb, XIb, rp, scv);
  gemm_k<4,1><<<NN,256,0,stream>>>(XSb, XIb, Wfc, bc, state, d_out, flag);
}